// Round 5
// baseline (3949.770 us; speedup 1.0000x reference)
//
#include <hip/hip_runtime.h>

#define IC 4096
#define IPW 2        // i-values register-cached per wave (64 VGPRs -- fits default budget)
#define SROW 260     // padded LDS row stride (floats); 16B-aligned rows, breaks bank repeat

// One routing pass. Block = 8 waves x IPW i-values = 16 i, half the batch (128 b).
// Per (b,i): u[a,d] = sum_c x[b,i,c]*W[a,i,d,c]; weight by c[a] (uniform 1/16 or
// softmax over a of IC*(u.vprev)); accumulate into LDS s-tile via ds_add_f32;
// flush tile to global replica via atomics every 64 b.
template<int USEV>
__global__ __launch_bounds__(512)
__attribute__((amdgpu_waves_per_eu(4, 4)))
void caps_pass(const float* __restrict__ x, const float* __restrict__ W,
               const float* __restrict__ vprev, float* __restrict__ s_rep,
               int n_rep)
{
    __shared__ float sts[64 * SROW];   // [64 b][260] s accumulation tile (~65 KB)
    const int tid  = threadIdx.x;
    const int wu   = __builtin_amdgcn_readfirstlane(tid >> 6);  // wave 0..7
    const int lane = tid & 63;
    const int a    = lane >> 2;   // capsule 0..15
    const int dq   = lane & 3;    // d-quad: lane owns d = dq*4 .. dq*4+3
    const int ichunk = (int)blockIdx.x >> 1;   // 0..255
    const int bhalf  = (int)blockIdx.x & 1;
    const int i0 = ichunk * (8 * IPW) + wu * IPW;
    const int rep = (int)blockIdx.x & (n_rep - 1);
    float* srep = s_rep + (size_t)rep * 65536;

    // Register-cache W[a, i0..i0+1, dq*4..dq*4+3, 0..7]: 32 contiguous floats per i.
    float w[IPW][32];
#pragma unroll
    for (int ii = 0; ii < IPW; ++ii) {
        const float* wp = W + ((size_t)a * IC + (size_t)(i0 + ii)) * 128 + dq * 32;
#pragma unroll
        for (int q = 0; q < 8; ++q) {
            const float4 f = *(const float4*)(wp + q * 4);
            w[ii][q * 4 + 0] = f.x; w[ii][q * 4 + 1] = f.y;
            w[ii][q * 4 + 2] = f.z; w[ii][q * 4 + 3] = f.w;
        }
    }
    // Pin: forbid rematerialization of the W loads inside the b loop.
    // 64 floats fits under the allocator's ~100-VGPR budget -> no spill expected.
#pragma unroll
    for (int ii = 0; ii < IPW; ++ii)
#pragma unroll
        for (int k = 0; k < 32; ++k)
            asm volatile("" : "+v"(w[ii][k]));

    const int b0 = bhalf * 128;
    const int tb = tid >> 3;          // 0..63: row for zero/flush
    const int tc = (tid & 7) * 32;    // 32-float column group

    for (int ch = 0; ch < 2; ++ch) {
        // zero the s-tile
        {
            float* zp = &sts[tb * SROW + tc];
            const float4 z = make_float4(0.f, 0.f, 0.f, 0.f);
#pragma unroll
            for (int k = 0; k < 8; ++k) *(float4*)(zp + k * 4) = z;
        }
        __syncthreads();

        const int bc0 = b0 + ch * 64;
        for (int bb = 0; bb < 64; ++bb) {
            const int b = bc0 + bb;
            float4 va;
            if (USEV)
                va = *(const float4*)(vprev + (((size_t)b * 16 + a) * 16 + dq * 4));
            float sl0 = 0.f, sl1 = 0.f, sl2 = 0.f, sl3 = 0.f;
#pragma unroll
            for (int ii = 0; ii < IPW; ++ii) {
                // uniform address across the wave -> scalar (s_load) x fetch
                const float* xp = x + ((size_t)b * IC + (size_t)(i0 + ii)) * 8;
                const float4 xa = *(const float4*)(xp);
                const float4 xb = *(const float4*)(xp + 4);
                float u0, u1, u2, u3;
                u0 = xa.x * w[ii][0];
                u1 = xa.x * w[ii][8];
                u2 = xa.x * w[ii][16];
                u3 = xa.x * w[ii][24];
                u0 = fmaf(xa.y, w[ii][1],  u0); u1 = fmaf(xa.y, w[ii][9],  u1);
                u2 = fmaf(xa.y, w[ii][17], u2); u3 = fmaf(xa.y, w[ii][25], u3);
                u0 = fmaf(xa.z, w[ii][2],  u0); u1 = fmaf(xa.z, w[ii][10], u1);
                u2 = fmaf(xa.z, w[ii][18], u2); u3 = fmaf(xa.z, w[ii][26], u3);
                u0 = fmaf(xa.w, w[ii][3],  u0); u1 = fmaf(xa.w, w[ii][11], u1);
                u2 = fmaf(xa.w, w[ii][19], u2); u3 = fmaf(xa.w, w[ii][27], u3);
                u0 = fmaf(xb.x, w[ii][4],  u0); u1 = fmaf(xb.x, w[ii][12], u1);
                u2 = fmaf(xb.x, w[ii][20], u2); u3 = fmaf(xb.x, w[ii][28], u3);
                u0 = fmaf(xb.y, w[ii][5],  u0); u1 = fmaf(xb.y, w[ii][13], u1);
                u2 = fmaf(xb.y, w[ii][21], u2); u3 = fmaf(xb.y, w[ii][29], u3);
                u0 = fmaf(xb.z, w[ii][6],  u0); u1 = fmaf(xb.z, w[ii][14], u1);
                u2 = fmaf(xb.z, w[ii][22], u2); u3 = fmaf(xb.z, w[ii][30], u3);
                u0 = fmaf(xb.w, w[ii][7],  u0); u1 = fmaf(xb.w, w[ii][15], u1);
                u2 = fmaf(xb.w, w[ii][23], u2); u3 = fmaf(xb.w, w[ii][31], u3);
                float cw;
                if (USEV == 0) {
                    cw = 1.0f / 16.0f;
                } else {
                    // agree = u . vprev (vprev = v1, or v1+v2 for the last pass)
                    float ag = u0 * va.x + u1 * va.y + u2 * va.z + u3 * va.w;
                    ag += __shfl_xor(ag, 1);   // combine d-quads within the a-group
                    ag += __shfl_xor(ag, 2);
                    const float blog = 4096.0f * ag;
                    // softmax over 16 capsules (4-lane groups); strides 4..32
                    // don't touch lane bits 0-1 so replicated values sum once per a.
                    float m = blog;
                    m = fmaxf(m, __shfl_xor(m, 4));
                    m = fmaxf(m, __shfl_xor(m, 8));
                    m = fmaxf(m, __shfl_xor(m, 16));
                    m = fmaxf(m, __shfl_xor(m, 32));
                    const float e = __expf(blog - m);
                    float sum = e;
                    sum += __shfl_xor(sum, 4);
                    sum += __shfl_xor(sum, 8);
                    sum += __shfl_xor(sum, 16);
                    sum += __shfl_xor(sum, 32);
                    cw = __fdividef(e, sum);
                }
                sl0 = fmaf(cw, u0, sl0);
                sl1 = fmaf(cw, u1, sl1);
                sl2 = fmaf(cw, u2, sl2);
                sl3 = fmaf(cw, u3, sl3);
            }
            // native LDS float atomics (ds_add_f32): all 8 waves accumulate
            // their i-contributions for this b directly into the tile.
            float* dst = &sts[bb * SROW + lane * 4];
            atomicAdd(dst + 0, sl0);
            atomicAdd(dst + 1, sl1);
            atomicAdd(dst + 2, sl2);
            atomicAdd(dst + 3, sl3);
        }
        __syncthreads();
        // flush tile -> global replica (one 32-float strip per thread, coalesced)
        {
            const float* sp2 = &sts[tb * SROW + tc];
            float* gd = srep + (size_t)(bc0 + tb) * 256 + tc;
#pragma unroll
            for (int k = 0; k < 8; ++k) {
                const float4 f = *(const float4*)(sp2 + k * 4);
                unsafeAtomicAdd(gd + k * 4 + 0, f.x);
                unsafeAtomicAdd(gd + k * 4 + 1, f.y);
                unsafeAtomicAdd(gd + k * 4 + 2, f.z);
                unsafeAtomicAdd(gd + k * 4 + 3, f.w);
            }
        }
        __syncthreads();
    }
}

// v = squash(sum_r s_rep[r]) [+ vprev]; optionally re-zero srep for next pass.
// One thread per (b, a): 4096 threads.
template<int ADDP, int ZERO>
__global__ void caps_squash(float* __restrict__ srep, int n_rep,
                            float* __restrict__ vout, const float* __restrict__ vprev)
{
    const int t = (int)blockIdx.x * 256 + (int)threadIdx.x;  // 0..4095
    float4 f0 = make_float4(0.f, 0.f, 0.f, 0.f), f1 = f0, f2 = f0, f3 = f0;
    for (int r = 0; r < n_rep; ++r) {
        float* sp = srep + (size_t)r * 65536 + (size_t)t * 16;
        const float4 a0 = *(const float4*)(sp + 0);
        const float4 a1 = *(const float4*)(sp + 4);
        const float4 a2 = *(const float4*)(sp + 8);
        const float4 a3 = *(const float4*)(sp + 12);
        f0.x += a0.x; f0.y += a0.y; f0.z += a0.z; f0.w += a0.w;
        f1.x += a1.x; f1.y += a1.y; f1.z += a1.z; f1.w += a1.w;
        f2.x += a2.x; f2.y += a2.y; f2.z += a2.z; f2.w += a2.w;
        f3.x += a3.x; f3.y += a3.y; f3.z += a3.z; f3.w += a3.w;
        if (ZERO) {
            const float4 z = make_float4(0.f, 0.f, 0.f, 0.f);
            *(float4*)(sp + 0) = z; *(float4*)(sp + 4) = z;
            *(float4*)(sp + 8) = z; *(float4*)(sp + 12) = z;
        }
    }
    float sq = f0.x * f0.x + f0.y * f0.y + f0.z * f0.z + f0.w * f0.w
             + f1.x * f1.x + f1.y * f1.y + f1.z * f1.z + f1.w * f1.w
             + f2.x * f2.x + f2.y * f2.y + f2.z * f2.z + f2.w * f2.w
             + f3.x * f3.x + f3.y * f3.y + f3.z * f3.z + f3.w * f3.w;
    const float scale = sq / ((1.0f + sq) * sqrtf(sq + 1e-7f));
    float4 o0, o1, o2, o3;
    o0.x = f0.x * scale; o0.y = f0.y * scale; o0.z = f0.z * scale; o0.w = f0.w * scale;
    o1.x = f1.x * scale; o1.y = f1.y * scale; o1.z = f1.z * scale; o1.w = f1.w * scale;
    o2.x = f2.x * scale; o2.y = f2.y * scale; o2.z = f2.z * scale; o2.w = f2.w * scale;
    o3.x = f3.x * scale; o3.y = f3.y * scale; o3.z = f3.z * scale; o3.w = f3.w * scale;
    if (ADDP) {
        const float* pp = vprev + (size_t)t * 16;
        const float4 p0 = *(const float4*)(pp + 0);
        const float4 p1 = *(const float4*)(pp + 4);
        const float4 p2 = *(const float4*)(pp + 8);
        const float4 p3 = *(const float4*)(pp + 12);
        o0.x += p0.x; o0.y += p0.y; o0.z += p0.z; o0.w += p0.w;
        o1.x += p1.x; o1.y += p1.y; o1.z += p1.z; o1.w += p1.w;
        o2.x += p2.x; o2.y += p2.y; o2.z += p2.z; o2.w += p2.w;
        o3.x += p3.x; o3.y += p3.y; o3.z += p3.z; o3.w += p3.w;
    }
    float* vp = vout + (size_t)t * 16;
    *(float4*)(vp + 0)  = o0;
    *(float4*)(vp + 4)  = o1;
    *(float4*)(vp + 8)  = o2;
    *(float4*)(vp + 12) = o3;
}

__global__ void caps_zero(float* __restrict__ p)
{
    *(float4*)(p + ((size_t)blockIdx.x * 256 + threadIdx.x) * 4) =
        make_float4(0.f, 0.f, 0.f, 0.f);
}

extern "C" void kernel_launch(void* const* d_in, const int* in_sizes, int n_in,
                              void* d_out, int out_size, void* d_ws, size_t ws_size,
                              hipStream_t stream)
{
    const float* x = (const float*)d_in[0];   // [256, 4096, 8]
    const float* W = (const float*)d_in[1];   // [16, 4096, 16, 8]
    float* out = (float*)d_out;               // [256, 16, 16]

    // pick replica count by available workspace: (R + 2) * 256 KB needed
    int R = 1;
    if (ws_size >= (size_t)(8 + 2) * 65536 * 4) R = 8;
    else if (ws_size >= (size_t)(2 + 2) * 65536 * 4) R = 2;

    float* srep = (float*)d_ws;               // R * 65536 floats
    float* v1   = srep + (size_t)R * 65536;
    float* vs   = v1 + 65536;

    caps_zero<<<R * 64, 256, 0, stream>>>(srep);
    // iter 1: uniform coupling c = 1/16
    caps_pass<0><<<512, 512, 0, stream>>>(x, W, nullptr, srep, R);
    caps_squash<0, 1><<<16, 256, 0, stream>>>(srep, R, v1, nullptr);   // v1 = squash(s); s=0
    // iter 2: logits = IC * (u . v1)
    caps_pass<1><<<512, 512, 0, stream>>>(x, W, v1, srep, R);
    caps_squash<1, 1><<<16, 256, 0, stream>>>(srep, R, vs, v1);        // vs = squash(s)+v1; s=0
    // iter 3: logits = IC * (u.v1 + u.v2) = IC * (u . vs)
    caps_pass<1><<<512, 512, 0, stream>>>(x, W, vs, srep, R);
    caps_squash<0, 0><<<16, 256, 0, stream>>>(srep, R, out, nullptr);  // out = squash(s)
}

// Round 7
// 629.533 us; speedup vs baseline: 6.2741x; 6.2741x over previous
//
#include <hip/hip_runtime.h>

#define IC 4096
typedef unsigned short u16;
typedef unsigned int   u32;

static __device__ __forceinline__ u16 f2h(float f) {
    _Float16 h = (_Float16)f;               // RNE
    u16 r; __builtin_memcpy(&r, &h, 2); return r;
}
static __device__ __forceinline__ float h2f(u16 h) {
    _Float16 x; __builtin_memcpy(&x, &h, 2); return (float)x;
}

// ---------------- primary path: dense partials, no atomics ----------------
// Block = 8 waves = 8 consecutive i; loops all 256 b. Per (b,i): recompute
// u[a,d], softmax-weight (or uniform 1/16), reduce the 8 waves' contributions
// in LDS every 4 b, store the block's partial s-tile (fp32 or fp16) to
// part[blockIdx]. P16=0: fp32 partials (128 MiB). P16=1: fp16 (64 MiB).
template<int USEV, int P16>
__global__ __launch_bounds__(512)
void caps_pass_part(const float* __restrict__ x, const float* __restrict__ W,
                    const float* __restrict__ vprev, void* __restrict__ part)
{
    __shared__ float lds[8][4][256];
    const int tid  = threadIdx.x;
    const int wu   = __builtin_amdgcn_readfirstlane(tid >> 6);  // wave 0..7
    const int lane = tid & 63;
    const int a    = lane >> 2;   // capsule 0..15
    const int dq   = lane & 3;    // d-quad: lane owns d = dq*4..dq*4+3
    const int i    = (int)blockIdx.x * 8 + wu;                  // this wave's i

    // W cache: 32 floats/lane -- fits under the allocator's natural ~84-VGPR
    // budget (rounds 2-5: anything bigger gets spilled or rematerialized).
    float w[32];
    {
        const float* wp = W + ((size_t)a * IC + i) * 128 + dq * 32;
#pragma unroll
        for (int q = 0; q < 8; ++q) {
            const float4 f = *(const float4*)(wp + q * 4);
            w[q*4+0] = f.x; w[q*4+1] = f.y; w[q*4+2] = f.z; w[q*4+3] = f.w;
        }
    }
#pragma unroll
    for (int k = 0; k < 32; ++k) asm volatile("" : "+v"(w[k]));  // no remat

    for (int ph = 0; ph < 64; ++ph) {
#pragma unroll 1
        for (int nb = 0; nb < 4; ++nb) {
            const int b = ph * 4 + nb;
            float4 va;
            if (USEV)
                va = *(const float4*)(vprev + (((size_t)b * 16 + a) * 16 + dq * 4));
            // wave-uniform x pointer -> scalar loads
            const float* xp = x + ((size_t)b * IC + i) * 8;
            const float4 xa = *(const float4*)(xp);
            const float4 xb = *(const float4*)(xp + 4);
            float u0, u1, u2, u3;
            u0 = xa.x * w[0];
            u1 = xa.x * w[8];
            u2 = xa.x * w[16];
            u3 = xa.x * w[24];
            u0 = fmaf(xa.y, w[1],  u0); u1 = fmaf(xa.y, w[9],  u1);
            u2 = fmaf(xa.y, w[17], u2); u3 = fmaf(xa.y, w[25], u3);
            u0 = fmaf(xa.z, w[2],  u0); u1 = fmaf(xa.z, w[10], u1);
            u2 = fmaf(xa.z, w[18], u2); u3 = fmaf(xa.z, w[26], u3);
            u0 = fmaf(xa.w, w[3],  u0); u1 = fmaf(xa.w, w[11], u1);
            u2 = fmaf(xa.w, w[19], u2); u3 = fmaf(xa.w, w[27], u3);
            u0 = fmaf(xb.x, w[4],  u0); u1 = fmaf(xb.x, w[12], u1);
            u2 = fmaf(xb.x, w[20], u2); u3 = fmaf(xb.x, w[28], u3);
            u0 = fmaf(xb.y, w[5],  u0); u1 = fmaf(xb.y, w[13], u1);
            u2 = fmaf(xb.y, w[21], u2); u3 = fmaf(xb.y, w[29], u3);
            u0 = fmaf(xb.z, w[6],  u0); u1 = fmaf(xb.z, w[14], u1);
            u2 = fmaf(xb.z, w[22], u2); u3 = fmaf(xb.z, w[30], u3);
            u0 = fmaf(xb.w, w[7],  u0); u1 = fmaf(xb.w, w[15], u1);
            u2 = fmaf(xb.w, w[23], u2); u3 = fmaf(xb.w, w[31], u3);
            float cw;
            if (USEV == 0) {
                cw = 1.0f / 16.0f;
            } else {
                // agree = u . vprev  (vprev = v1, or v1+v2 for the last pass)
                float ag = u0 * va.x + u1 * va.y + u2 * va.z + u3 * va.w;
                ag += __shfl_xor(ag, 1);   // combine d-quads within the a-group
                ag += __shfl_xor(ag, 2);
                const float blog = 4096.0f * ag;
                // softmax over 16 capsules (4-lane groups); strides 4..32 keep
                // lane bits 0-1 fixed, so replicated values fold once per a.
                float m = blog;
                m = fmaxf(m, __shfl_xor(m, 4));
                m = fmaxf(m, __shfl_xor(m, 8));
                m = fmaxf(m, __shfl_xor(m, 16));
                m = fmaxf(m, __shfl_xor(m, 32));
                const float e = __expf(blog - m);
                float sum = e;
                sum += __shfl_xor(sum, 4);
                sum += __shfl_xor(sum, 8);
                sum += __shfl_xor(sum, 16);
                sum += __shfl_xor(sum, 32);
                cw = __fdividef(e, sum);
            }
            // straight to LDS (ds_write_b128: measured conflict-free r1-r4)
            float4 r;
            r.x = cw * u0; r.y = cw * u1; r.z = cw * u2; r.w = cw * u3;
            *(float4*)&lds[wu][nb][lane * 4] = r;
        }
        __syncthreads();
        if (tid < 256) {
            const int bsel = tid >> 6;          // 0..3
            const int ad4  = (tid & 63) * 4;    // 0..252
            float4 acc = make_float4(0.f, 0.f, 0.f, 0.f);
#pragma unroll
            for (int wv = 0; wv < 8; ++wv) {
                const float4 f = *(const float4*)&lds[wv][bsel][ad4];
                acc.x += f.x; acc.y += f.y; acc.z += f.z; acc.w += f.w;
            }
            const size_t off = (size_t)(ph * 4 + bsel) * 256 + ad4;
            if (P16) {
                ushort4 pk;
                pk.x = f2h(acc.x); pk.y = f2h(acc.y);
                pk.z = f2h(acc.z); pk.w = f2h(acc.w);
                *(ushort4*)((u16*)part + (size_t)blockIdx.x * 65536 + off) = pk;
            } else {
                *(float4*)((float*)part + (size_t)blockIdx.x * 65536 + off) = acc;
            }
        }
        __syncthreads();
    }
}

// Fused 512-deep partial reduction + squash. Thread = (b, a, d-pair):
// 32768 threads; d-norm via shfl_xor over the 8 d-pair lanes.
template<int ADDP, int P16>
__global__ __launch_bounds__(256)
void caps_squash_part(const void* __restrict__ part, float* __restrict__ vout,
                      const float* __restrict__ vprev)
{
    const int gt = (int)blockIdx.x * 256 + (int)threadIdx.x;  // 0..32767
    const int b  = gt >> 7;
    const int r  = gt & 127;                                  // a*8 + dpair
    float f0 = 0.f, f1 = 0.f;
    if (P16) {
        const u32* pp = (const u32*)part + (size_t)b * 128 + r;
#pragma unroll 8
        for (int ic = 0; ic < 512; ++ic) {
            const u32 raw = pp[(size_t)ic * 32768];
            f0 += h2f((u16)(raw & 0xffffu));
            f1 += h2f((u16)(raw >> 16));
        }
    } else {
        const float* pp = (const float*)part + (size_t)b * 256 + r * 2;
#pragma unroll 8
        for (int ic = 0; ic < 512; ++ic) {
            const float2 v = *(const float2*)(pp + (size_t)ic * 65536);
            f0 += v.x; f1 += v.y;
        }
    }
    float sq = f0 * f0 + f1 * f1;
    sq += __shfl_xor(sq, 1);
    sq += __shfl_xor(sq, 2);
    sq += __shfl_xor(sq, 4);
    const float scale = sq / ((1.0f + sq) * sqrtf(sq + 1e-7f));
    float o0 = f0 * scale, o1 = f1 * scale;
    if (ADDP) {
        const float2 p = *(const float2*)(vprev + (size_t)b * 256 + r * 2);
        o0 += p.x; o1 += p.y;
    }
    *(float2*)(vout + (size_t)b * 256 + r * 2) = make_float2(o0, o1);
}

// ---------------- legacy fallback (round-4, known-good) ----------------
template<int USEV>
__global__ __launch_bounds__(512)
void legacy_pass(const float* __restrict__ x, const float* __restrict__ W,
                 const float* __restrict__ vprev, float* __restrict__ s_rep,
                 int n_rep)
{
    __shared__ float lds[8][4][256];
    const int tid  = threadIdx.x;
    const int wu   = __builtin_amdgcn_readfirstlane(tid >> 6);
    const int lane = tid & 63;
    const int a    = lane >> 2;
    const int dq   = lane & 3;
    const int ichunk = (int)blockIdx.x >> 1;
    const int bhalf  = (int)blockIdx.x & 1;
    const int i0 = ichunk * 32 + wu * 4;
    const int rep = (int)blockIdx.x & (n_rep - 1);
    float* srep = s_rep + (size_t)rep * 65536;

    float w[4][32];
#pragma unroll
    for (int ii = 0; ii < 4; ++ii) {
        const float* wp = W + ((size_t)a * IC + (size_t)(i0 + ii)) * 128 + dq * 32;
#pragma unroll
        for (int q = 0; q < 8; ++q) {
            const float4 f = *(const float4*)(wp + q * 4);
            w[ii][q*4+0]=f.x; w[ii][q*4+1]=f.y; w[ii][q*4+2]=f.z; w[ii][q*4+3]=f.w;
        }
    }
#pragma unroll
    for (int ii = 0; ii < 4; ++ii)
#pragma unroll
        for (int k = 0; k < 32; ++k) asm volatile("" : "+v"(w[ii][k]));

    const int b0 = bhalf * 128;
    for (int ph = 0; ph < 32; ++ph) {
        float sl[4][4];
#pragma unroll
        for (int nb = 0; nb < 4; ++nb) {
            sl[nb][0]=0.f; sl[nb][1]=0.f; sl[nb][2]=0.f; sl[nb][3]=0.f;
            const int b = b0 + ph * 4 + nb;
            float4 va;
            if (USEV)
                va = *(const float4*)(vprev + (((size_t)b * 16 + a) * 16 + dq * 4));
#pragma unroll
            for (int ii = 0; ii < 4; ++ii) {
                const float* xp = x + ((size_t)b * IC + (size_t)(i0 + ii)) * 8;
                const float4 xa = *(const float4*)(xp);
                const float4 xb = *(const float4*)(xp + 4);
                float u0, u1, u2, u3;
                u0 = xa.x * w[ii][0];  u1 = xa.x * w[ii][8];
                u2 = xa.x * w[ii][16]; u3 = xa.x * w[ii][24];
                u0 = fmaf(xa.y, w[ii][1],  u0); u1 = fmaf(xa.y, w[ii][9],  u1);
                u2 = fmaf(xa.y, w[ii][17], u2); u3 = fmaf(xa.y, w[ii][25], u3);
                u0 = fmaf(xa.z, w[ii][2],  u0); u1 = fmaf(xa.z, w[ii][10], u1);
                u2 = fmaf(xa.z, w[ii][18], u2); u3 = fmaf(xa.z, w[ii][26], u3);
                u0 = fmaf(xa.w, w[ii][3],  u0); u1 = fmaf(xa.w, w[ii][11], u1);
                u2 = fmaf(xa.w, w[ii][19], u2); u3 = fmaf(xa.w, w[ii][27], u3);
                u0 = fmaf(xb.x, w[ii][4],  u0); u1 = fmaf(xb.x, w[ii][12], u1);
                u2 = fmaf(xb.x, w[ii][20], u2); u3 = fmaf(xb.x, w[ii][28], u3);
                u0 = fmaf(xb.y, w[ii][5],  u0); u1 = fmaf(xb.y, w[ii][13], u1);
                u2 = fmaf(xb.y, w[ii][21], u2); u3 = fmaf(xb.y, w[ii][29], u3);
                u0 = fmaf(xb.z, w[ii][6],  u0); u1 = fmaf(xb.z, w[ii][14], u1);
                u2 = fmaf(xb.z, w[ii][22], u2); u3 = fmaf(xb.z, w[ii][30], u3);
                u0 = fmaf(xb.w, w[ii][7],  u0); u1 = fmaf(xb.w, w[ii][15], u1);
                u2 = fmaf(xb.w, w[ii][23], u2); u3 = fmaf(xb.w, w[ii][31], u3);
                float cw;
                if (USEV == 0) {
                    cw = 1.0f / 16.0f;
                } else {
                    float ag = u0*va.x + u1*va.y + u2*va.z + u3*va.w;
                    ag += __shfl_xor(ag, 1);
                    ag += __shfl_xor(ag, 2);
                    const float blog = 4096.0f * ag;
                    float m = blog;
                    m = fmaxf(m, __shfl_xor(m, 4));
                    m = fmaxf(m, __shfl_xor(m, 8));
                    m = fmaxf(m, __shfl_xor(m, 16));
                    m = fmaxf(m, __shfl_xor(m, 32));
                    const float e = __expf(blog - m);
                    float sum = e;
                    sum += __shfl_xor(sum, 4);
                    sum += __shfl_xor(sum, 8);
                    sum += __shfl_xor(sum, 16);
                    sum += __shfl_xor(sum, 32);
                    cw = __fdividef(e, sum);
                }
                sl[nb][0] = fmaf(cw, u0, sl[nb][0]);
                sl[nb][1] = fmaf(cw, u1, sl[nb][1]);
                sl[nb][2] = fmaf(cw, u2, sl[nb][2]);
                sl[nb][3] = fmaf(cw, u3, sl[nb][3]);
            }
        }
#pragma unroll
        for (int nb = 0; nb < 4; ++nb)
            *(float4*)&lds[wu][nb][lane * 4] =
                make_float4(sl[nb][0], sl[nb][1], sl[nb][2], sl[nb][3]);
        __syncthreads();
        if (tid < 256) {
            const int bsel = tid >> 6;
            const int ad4  = (tid & 63) * 4;
            float4 acc = make_float4(0.f, 0.f, 0.f, 0.f);
#pragma unroll
            for (int wv = 0; wv < 8; ++wv) {
                const float4 f = *(const float4*)&lds[wv][bsel][ad4];
                acc.x += f.x; acc.y += f.y; acc.z += f.z; acc.w += f.w;
            }
            float* dst = srep + (size_t)(b0 + ph * 4 + bsel) * 256 + ad4;
            unsafeAtomicAdd(dst + 0, acc.x);
            unsafeAtomicAdd(dst + 1, acc.y);
            unsafeAtomicAdd(dst + 2, acc.z);
            unsafeAtomicAdd(dst + 3, acc.w);
        }
        __syncthreads();
    }
}

template<int ADDP, int ZERO>
__global__ void legacy_squash(float* __restrict__ srep, int n_rep,
                              float* __restrict__ vout, const float* __restrict__ vprev)
{
    const int t = (int)blockIdx.x * 256 + (int)threadIdx.x;
    float4 f0 = make_float4(0.f,0.f,0.f,0.f), f1 = f0, f2 = f0, f3 = f0;
    for (int r = 0; r < n_rep; ++r) {
        float* sp = srep + (size_t)r * 65536 + (size_t)t * 16;
        const float4 a0 = *(const float4*)(sp + 0);
        const float4 a1 = *(const float4*)(sp + 4);
        const float4 a2 = *(const float4*)(sp + 8);
        const float4 a3 = *(const float4*)(sp + 12);
        f0.x+=a0.x; f0.y+=a0.y; f0.z+=a0.z; f0.w+=a0.w;
        f1.x+=a1.x; f1.y+=a1.y; f1.z+=a1.z; f1.w+=a1.w;
        f2.x+=a2.x; f2.y+=a2.y; f2.z+=a2.z; f2.w+=a2.w;
        f3.x+=a3.x; f3.y+=a3.y; f3.z+=a3.z; f3.w+=a3.w;
        if (ZERO) {
            const float4 z = make_float4(0.f,0.f,0.f,0.f);
            *(float4*)(sp+0)=z; *(float4*)(sp+4)=z; *(float4*)(sp+8)=z; *(float4*)(sp+12)=z;
        }
    }
    float sq = f0.x*f0.x+f0.y*f0.y+f0.z*f0.z+f0.w*f0.w
             + f1.x*f1.x+f1.y*f1.y+f1.z*f1.z+f1.w*f1.w
             + f2.x*f2.x+f2.y*f2.y+f2.z*f2.z+f2.w*f2.w
             + f3.x*f3.x+f3.y*f3.y+f3.z*f3.z+f3.w*f3.w;
    const float scale = sq / ((1.0f + sq) * sqrtf(sq + 1e-7f));
    float4 o0, o1, o2, o3;
    o0.x=f0.x*scale; o0.y=f0.y*scale; o0.z=f0.z*scale; o0.w=f0.w*scale;
    o1.x=f1.x*scale; o1.y=f1.y*scale; o1.z=f1.z*scale; o1.w=f1.w*scale;
    o2.x=f2.x*scale; o2.y=f2.y*scale; o2.z=f2.z*scale; o2.w=f2.w*scale;
    o3.x=f3.x*scale; o3.y=f3.y*scale; o3.z=f3.z*scale; o3.w=f3.w*scale;
    if (ADDP) {
        const float* pp = vprev + (size_t)t * 16;
        const float4 p0 = *(const float4*)(pp + 0);
        const float4 p1 = *(const float4*)(pp + 4);
        const float4 p2 = *(const float4*)(pp + 8);
        const float4 p3 = *(const float4*)(pp + 12);
        o0.x+=p0.x; o0.y+=p0.y; o0.z+=p0.z; o0.w+=p0.w;
        o1.x+=p1.x; o1.y+=p1.y; o1.z+=p1.z; o1.w+=p1.w;
        o2.x+=p2.x; o2.y+=p2.y; o2.z+=p2.z; o2.w+=p2.w;
        o3.x+=p3.x; o3.y+=p3.y; o3.z+=p3.z; o3.w+=p3.w;
    }
    float* vp = vout + (size_t)t * 16;
    *(float4*)(vp+0)=o0; *(float4*)(vp+4)=o1; *(float4*)(vp+8)=o2; *(float4*)(vp+12)=o3;
}

__global__ void legacy_zero(float* __restrict__ p)
{
    *(float4*)(p + ((size_t)blockIdx.x * 256 + threadIdx.x) * 4) =
        make_float4(0.f, 0.f, 0.f, 0.f);
}

extern "C" void kernel_launch(void* const* d_in, const int* in_sizes, int n_in,
                              void* d_out, int out_size, void* d_ws, size_t ws_size,
                              hipStream_t stream)
{
    const float* x = (const float*)d_in[0];   // [256, 4096, 8]
    const float* W = (const float*)d_in[1];   // [16, 4096, 16, 8]
    float* out = (float*)d_out;               // [256, 16, 16]

    const size_t need32 = (size_t)512 * 65536 * 4 + 2 * 65536 * 4;  // 128.5 MiB
    const size_t need16 = (size_t)512 * 65536 * 2 + 2 * 65536 * 4;  //  64.5 MiB

    if (ws_size >= need32) {
        // fp32 partials: numerically identical to the round-4 path (passed at ~5e-4)
        float* part = (float*)d_ws;
        float* v1   = part + (size_t)512 * 65536;
        float* vs   = v1 + 65536;
        caps_pass_part<0, 0><<<512, 512, 0, stream>>>(x, W, nullptr, part);
        caps_squash_part<0, 0><<<128, 256, 0, stream>>>(part, v1, nullptr);
        caps_pass_part<1, 0><<<512, 512, 0, stream>>>(x, W, v1, part);
        caps_squash_part<1, 0><<<128, 256, 0, stream>>>(part, vs, v1);
        caps_pass_part<1, 0><<<512, 512, 0, stream>>>(x, W, vs, part);
        caps_squash_part<0, 0><<<128, 256, 0, stream>>>(part, out, nullptr);
    } else if (ws_size >= need16) {
        // fp16 partials: 8x finer than the bf16 that failed round 6 (2.1e-2),
        // predicted ~2.7e-3 output error vs 1.7e-2 threshold.
        u16*  part = (u16*)d_ws;
        float* v1  = (float*)((char*)d_ws + (size_t)512 * 65536 * 2);
        float* vs  = v1 + 65536;
        caps_pass_part<0, 1><<<512, 512, 0, stream>>>(x, W, nullptr, part);
        caps_squash_part<0, 1><<<128, 256, 0, stream>>>(part, v1, nullptr);
        caps_pass_part<1, 1><<<512, 512, 0, stream>>>(x, W, v1, part);
        caps_squash_part<1, 1><<<128, 256, 0, stream>>>(part, vs, v1);
        caps_pass_part<1, 1><<<512, 512, 0, stream>>>(x, W, vs, part);
        caps_squash_part<0, 1><<<128, 256, 0, stream>>>(part, out, nullptr);
    } else {
        int R = 1;
        if (ws_size >= (size_t)(8 + 2) * 65536 * 4) R = 8;
        else if (ws_size >= (size_t)(2 + 2) * 65536 * 4) R = 2;
        float* srep = (float*)d_ws;
        float* v1   = srep + (size_t)R * 65536;
        float* vs   = v1 + 65536;
        legacy_zero<<<R * 64, 256, 0, stream>>>(srep);
        legacy_pass<0><<<256, 512, 0, stream>>>(x, W, nullptr, srep, R);
        legacy_squash<0, 1><<<16, 256, 0, stream>>>(srep, R, v1, nullptr);
        legacy_pass<1><<<256, 512, 0, stream>>>(x, W, v1, srep, R);
        legacy_squash<1, 1><<<16, 256, 0, stream>>>(srep, R, vs, v1);
        legacy_pass<1><<<256, 512, 0, stream>>>(x, W, vs, srep, R);
        legacy_squash<0, 0><<<16, 256, 0, stream>>>(srep, R, out, nullptr);
    }
}

// Round 8
// 489.936 us; speedup vs baseline: 8.0618x; 1.2849x over previous
//
#include <hip/hip_runtime.h>

#define IC 4096
typedef unsigned short u16;
typedef unsigned int   u32;

static __device__ __forceinline__ u16 f2h(float f) {
    _Float16 h = (_Float16)f;               // RNE
    u16 r; __builtin_memcpy(&r, &h, 2); return r;
}
static __device__ __forceinline__ float h2f(u16 h) {
    _Float16 x; __builtin_memcpy(&x, &h, 2); return (float)x;
}

// ---------------- primary path: dense partials, no atomics ----------------
// Grid = 1024 blocks: (i-chunk 0..511) x (b-half 0..1). Block = 8 waves = 8 i,
// loops 128 b. Per (b,i): recompute u[a,d], softmax-weight (or uniform 1/16),
// reduce the 8 waves' contributions in LDS every 4 b, store the block's
// partial s-tile (fp32 or fp16) to part[blockIdx] (128 b x 256 each).
// The 4 b's of a phase are fully unrolled: 4 independent softmax shfl-chains
// interleave, hiding the ~350-cycle serial latency that capped round 7.
template<int USEV, int P16>
__global__ __launch_bounds__(512)
void caps_pass_part(const float* __restrict__ x, const float* __restrict__ W,
                    const float* __restrict__ vprev, void* __restrict__ part)
{
    __shared__ float lds[8][4][256];
    const int tid  = threadIdx.x;
    const int wu   = __builtin_amdgcn_readfirstlane(tid >> 6);  // wave 0..7
    const int lane = tid & 63;
    const int a    = lane >> 2;   // capsule 0..15
    const int dq   = lane & 3;    // d-quad: lane owns d = dq*4..dq*4+3
    const int ib   = (int)blockIdx.x & 511;   // i-chunk
    const int bh   = (int)blockIdx.x >> 9;    // b-half
    const int i    = ib * 8 + wu;             // this wave's i

    // W cache: 32 floats/lane -- fits under the allocator's natural budget
    // (rounds 2-5: anything bigger gets spilled or rematerialized).
    float w[32];
    {
        const float* wp = W + ((size_t)a * IC + i) * 128 + dq * 32;
#pragma unroll
        for (int q = 0; q < 8; ++q) {
            const float4 f = *(const float4*)(wp + q * 4);
            w[q*4+0] = f.x; w[q*4+1] = f.y; w[q*4+2] = f.z; w[q*4+3] = f.w;
        }
    }
#pragma unroll
    for (int k = 0; k < 32; ++k) asm volatile("" : "+v"(w[k]));  // no remat

    const int b0 = bh * 128;

    for (int ph = 0; ph < 32; ++ph) {
        // prefetch all 4 b's inputs (independent, loads overlap)
        float4 xa[4], xb[4], va[4];
#pragma unroll
        for (int nb = 0; nb < 4; ++nb) {
            const int b = b0 + ph * 4 + nb;
            const float* xp = x + ((size_t)b * IC + i) * 8;   // wave-uniform
            xa[nb] = *(const float4*)(xp);
            xb[nb] = *(const float4*)(xp + 4);
            if (USEV)
                va[nb] = *(const float4*)(vprev + (((size_t)b * 16 + a) * 16 + dq * 4));
        }
#pragma unroll
        for (int nb = 0; nb < 4; ++nb) {
            float u0, u1, u2, u3;
            u0 = xa[nb].x * w[0];
            u1 = xa[nb].x * w[8];
            u2 = xa[nb].x * w[16];
            u3 = xa[nb].x * w[24];
            u0 = fmaf(xa[nb].y, w[1],  u0); u1 = fmaf(xa[nb].y, w[9],  u1);
            u2 = fmaf(xa[nb].y, w[17], u2); u3 = fmaf(xa[nb].y, w[25], u3);
            u0 = fmaf(xa[nb].z, w[2],  u0); u1 = fmaf(xa[nb].z, w[10], u1);
            u2 = fmaf(xa[nb].z, w[18], u2); u3 = fmaf(xa[nb].z, w[26], u3);
            u0 = fmaf(xa[nb].w, w[3],  u0); u1 = fmaf(xa[nb].w, w[11], u1);
            u2 = fmaf(xa[nb].w, w[19], u2); u3 = fmaf(xa[nb].w, w[27], u3);
            u0 = fmaf(xb[nb].x, w[4],  u0); u1 = fmaf(xb[nb].x, w[12], u1);
            u2 = fmaf(xb[nb].x, w[20], u2); u3 = fmaf(xb[nb].x, w[28], u3);
            u0 = fmaf(xb[nb].y, w[5],  u0); u1 = fmaf(xb[nb].y, w[13], u1);
            u2 = fmaf(xb[nb].y, w[21], u2); u3 = fmaf(xb[nb].y, w[29], u3);
            u0 = fmaf(xb[nb].z, w[6],  u0); u1 = fmaf(xb[nb].z, w[14], u1);
            u2 = fmaf(xb[nb].z, w[22], u2); u3 = fmaf(xb[nb].z, w[30], u3);
            u0 = fmaf(xb[nb].w, w[7],  u0); u1 = fmaf(xb[nb].w, w[15], u1);
            u2 = fmaf(xb[nb].w, w[23], u2); u3 = fmaf(xb[nb].w, w[31], u3);
            float cw;
            if (USEV == 0) {
                cw = 1.0f / 16.0f;
            } else {
                // agree = u . vprev  (vprev = v1, or v1+v2 for the last pass)
                float ag = u0 * va[nb].x + u1 * va[nb].y + u2 * va[nb].z + u3 * va[nb].w;
                ag += __shfl_xor(ag, 1);   // combine d-quads within the a-group
                ag += __shfl_xor(ag, 2);
                const float blog = 4096.0f * ag;
                // softmax over 16 capsules (4-lane groups); strides 4..32 keep
                // lane bits 0-1 fixed, so replicated values fold once per a.
                float m = blog;
                m = fmaxf(m, __shfl_xor(m, 4));
                m = fmaxf(m, __shfl_xor(m, 8));
                m = fmaxf(m, __shfl_xor(m, 16));
                m = fmaxf(m, __shfl_xor(m, 32));
                const float e = __expf(blog - m);
                float sum = e;
                sum += __shfl_xor(sum, 4);
                sum += __shfl_xor(sum, 8);
                sum += __shfl_xor(sum, 16);
                sum += __shfl_xor(sum, 32);
                cw = __fdividef(e, sum);
            }
            // straight to LDS (ds_write_b128: measured conflict-free r1-r7)
            float4 r;
            r.x = cw * u0; r.y = cw * u1; r.z = cw * u2; r.w = cw * u3;
            *(float4*)&lds[wu][nb][lane * 4] = r;
        }
        __syncthreads();
        if (tid < 256) {
            const int bsel = tid >> 6;          // 0..3
            const int ad4  = (tid & 63) * 4;    // 0..252
            float4 acc = make_float4(0.f, 0.f, 0.f, 0.f);
#pragma unroll
            for (int wv = 0; wv < 8; ++wv) {
                const float4 f = *(const float4*)&lds[wv][bsel][ad4];
                acc.x += f.x; acc.y += f.y; acc.z += f.z; acc.w += f.w;
            }
            const size_t off = (size_t)(ph * 4 + bsel) * 256 + ad4;  // local b * 256
            if (P16) {
                ushort4 pk;
                pk.x = f2h(acc.x); pk.y = f2h(acc.y);
                pk.z = f2h(acc.z); pk.w = f2h(acc.w);
                *(ushort4*)((u16*)part + (size_t)blockIdx.x * 32768 + off) = pk;
            } else {
                *(float4*)((float*)part + (size_t)blockIdx.x * 32768 + off) = acc;
            }
        }
        __syncthreads();
    }
}

// Fused 512-deep partial reduction + squash. Thread = (b, a, d-pair):
// 32768 threads; d-norm via shfl_xor over the 8 d-pair lanes.
// Output b's partials live in the 512 tiles of its b-half.
template<int ADDP, int P16>
__global__ __launch_bounds__(256)
void caps_squash_part(const void* __restrict__ part, float* __restrict__ vout,
                      const float* __restrict__ vprev)
{
    const int gt = (int)blockIdx.x * 256 + (int)threadIdx.x;  // 0..32767
    const int b  = gt >> 7;
    const int r  = gt & 127;                                  // a*8 + dpair
    const int h  = b >> 7;                                    // b-half
    const int lb = b & 127;                                   // local b in tile
    float f0 = 0.f, f1 = 0.f;
    if (P16) {
        const u32* pp = (const u32*)part + ((size_t)h * 512) * 16384
                      + (size_t)lb * 128 + r;
#pragma unroll 8
        for (int ic = 0; ic < 512; ++ic) {
            const u32 raw = pp[(size_t)ic * 16384];
            f0 += h2f((u16)(raw & 0xffffu));
            f1 += h2f((u16)(raw >> 16));
        }
    } else {
        const float* pp = (const float*)part + ((size_t)h * 512) * 32768
                        + (size_t)lb * 256 + r * 2;
#pragma unroll 8
        for (int ic = 0; ic < 512; ++ic) {
            const float2 v = *(const float2*)(pp + (size_t)ic * 32768);
            f0 += v.x; f1 += v.y;
        }
    }
    float sq = f0 * f0 + f1 * f1;
    sq += __shfl_xor(sq, 1);
    sq += __shfl_xor(sq, 2);
    sq += __shfl_xor(sq, 4);
    const float scale = sq / ((1.0f + sq) * sqrtf(sq + 1e-7f));
    float o0 = f0 * scale, o1 = f1 * scale;
    if (ADDP) {
        const float2 p = *(const float2*)(vprev + (size_t)b * 256 + r * 2);
        o0 += p.x; o1 += p.y;
    }
    *(float2*)(vout + (size_t)b * 256 + r * 2) = make_float2(o0, o1);
}

// ---------------- legacy fallback (round-4, known-good) ----------------
template<int USEV>
__global__ __launch_bounds__(512)
void legacy_pass(const float* __restrict__ x, const float* __restrict__ W,
                 const float* __restrict__ vprev, float* __restrict__ s_rep,
                 int n_rep)
{
    __shared__ float lds[8][4][256];
    const int tid  = threadIdx.x;
    const int wu   = __builtin_amdgcn_readfirstlane(tid >> 6);
    const int lane = tid & 63;
    const int a    = lane >> 2;
    const int dq   = lane & 3;
    const int ichunk = (int)blockIdx.x >> 1;
    const int bhalf  = (int)blockIdx.x & 1;
    const int i0 = ichunk * 32 + wu * 4;
    const int rep = (int)blockIdx.x & (n_rep - 1);
    float* srep = s_rep + (size_t)rep * 65536;

    float w[4][32];
#pragma unroll
    for (int ii = 0; ii < 4; ++ii) {
        const float* wp = W + ((size_t)a * IC + (size_t)(i0 + ii)) * 128 + dq * 32;
#pragma unroll
        for (int q = 0; q < 8; ++q) {
            const float4 f = *(const float4*)(wp + q * 4);
            w[ii][q*4+0]=f.x; w[ii][q*4+1]=f.y; w[ii][q*4+2]=f.z; w[ii][q*4+3]=f.w;
        }
    }
#pragma unroll
    for (int ii = 0; ii < 4; ++ii)
#pragma unroll
        for (int k = 0; k < 32; ++k) asm volatile("" : "+v"(w[ii][k]));

    const int b0 = bhalf * 128;
    for (int ph = 0; ph < 32; ++ph) {
        float sl[4][4];
#pragma unroll
        for (int nb = 0; nb < 4; ++nb) {
            sl[nb][0]=0.f; sl[nb][1]=0.f; sl[nb][2]=0.f; sl[nb][3]=0.f;
            const int b = b0 + ph * 4 + nb;
            float4 va;
            if (USEV)
                va = *(const float4*)(vprev + (((size_t)b * 16 + a) * 16 + dq * 4));
#pragma unroll
            for (int ii = 0; ii < 4; ++ii) {
                const float* xp = x + ((size_t)b * IC + (size_t)(i0 + ii)) * 8;
                const float4 xa = *(const float4*)(xp);
                const float4 xb = *(const float4*)(xp + 4);
                float u0, u1, u2, u3;
                u0 = xa.x * w[ii][0];  u1 = xa.x * w[ii][8];
                u2 = xa.x * w[ii][16]; u3 = xa.x * w[ii][24];
                u0 = fmaf(xa.y, w[ii][1],  u0); u1 = fmaf(xa.y, w[ii][9],  u1);
                u2 = fmaf(xa.y, w[ii][17], u2); u3 = fmaf(xa.y, w[ii][25], u3);
                u0 = fmaf(xa.z, w[ii][2],  u0); u1 = fmaf(xa.z, w[ii][10], u1);
                u2 = fmaf(xa.z, w[ii][18], u2); u3 = fmaf(xa.z, w[ii][26], u3);
                u0 = fmaf(xa.w, w[ii][3],  u0); u1 = fmaf(xa.w, w[ii][11], u1);
                u2 = fmaf(xa.w, w[ii][19], u2); u3 = fmaf(xa.w, w[ii][27], u3);
                u0 = fmaf(xb.x, w[ii][4],  u0); u1 = fmaf(xb.x, w[ii][12], u1);
                u2 = fmaf(xb.x, w[ii][20], u2); u3 = fmaf(xb.x, w[ii][28], u3);
                u0 = fmaf(xb.y, w[ii][5],  u0); u1 = fmaf(xb.y, w[ii][13], u1);
                u2 = fmaf(xb.y, w[ii][21], u2); u3 = fmaf(xb.y, w[ii][29], u3);
                u0 = fmaf(xb.z, w[ii][6],  u0); u1 = fmaf(xb.z, w[ii][14], u1);
                u2 = fmaf(xb.z, w[ii][22], u2); u3 = fmaf(xb.z, w[ii][30], u3);
                u0 = fmaf(xb.w, w[ii][7],  u0); u1 = fmaf(xb.w, w[ii][15], u1);
                u2 = fmaf(xb.w, w[ii][23], u2); u3 = fmaf(xb.w, w[ii][31], u3);
                float cw;
                if (USEV == 0) {
                    cw = 1.0f / 16.0f;
                } else {
                    float ag = u0*va.x + u1*va.y + u2*va.z + u3*va.w;
                    ag += __shfl_xor(ag, 1);
                    ag += __shfl_xor(ag, 2);
                    const float blog = 4096.0f * ag;
                    float m = blog;
                    m = fmaxf(m, __shfl_xor(m, 4));
                    m = fmaxf(m, __shfl_xor(m, 8));
                    m = fmaxf(m, __shfl_xor(m, 16));
                    m = fmaxf(m, __shfl_xor(m, 32));
                    const float e = __expf(blog - m);
                    float sum = e;
                    sum += __shfl_xor(sum, 4);
                    sum += __shfl_xor(sum, 8);
                    sum += __shfl_xor(sum, 16);
                    sum += __shfl_xor(sum, 32);
                    cw = __fdividef(e, sum);
                }
                sl[nb][0] = fmaf(cw, u0, sl[nb][0]);
                sl[nb][1] = fmaf(cw, u1, sl[nb][1]);
                sl[nb][2] = fmaf(cw, u2, sl[nb][2]);
                sl[nb][3] = fmaf(cw, u3, sl[nb][3]);
            }
        }
#pragma unroll
        for (int nb = 0; nb < 4; ++nb)
            *(float4*)&lds[wu][nb][lane * 4] =
                make_float4(sl[nb][0], sl[nb][1], sl[nb][2], sl[nb][3]);
        __syncthreads();
        if (tid < 256) {
            const int bsel = tid >> 6;
            const int ad4  = (tid & 63) * 4;
            float4 acc = make_float4(0.f, 0.f, 0.f, 0.f);
#pragma unroll
            for (int wv = 0; wv < 8; ++wv) {
                const float4 f = *(const float4*)&lds[wv][bsel][ad4];
                acc.x += f.x; acc.y += f.y; acc.z += f.z; acc.w += f.w;
            }
            float* dst = srep + (size_t)(b0 + ph * 4 + bsel) * 256 + ad4;
            unsafeAtomicAdd(dst + 0, acc.x);
            unsafeAtomicAdd(dst + 1, acc.y);
            unsafeAtomicAdd(dst + 2, acc.z);
            unsafeAtomicAdd(dst + 3, acc.w);
        }
        __syncthreads();
    }
}

template<int ADDP, int ZERO>
__global__ void legacy_squash(float* __restrict__ srep, int n_rep,
                              float* __restrict__ vout, const float* __restrict__ vprev)
{
    const int t = (int)blockIdx.x * 256 + (int)threadIdx.x;
    float4 f0 = make_float4(0.f,0.f,0.f,0.f), f1 = f0, f2 = f0, f3 = f0;
    for (int r = 0; r < n_rep; ++r) {
        float* sp = srep + (size_t)r * 65536 + (size_t)t * 16;
        const float4 a0 = *(const float4*)(sp + 0);
        const float4 a1 = *(const float4*)(sp + 4);
        const float4 a2 = *(const float4*)(sp + 8);
        const float4 a3 = *(const float4*)(sp + 12);
        f0.x+=a0.x; f0.y+=a0.y; f0.z+=a0.z; f0.w+=a0.w;
        f1.x+=a1.x; f1.y+=a1.y; f1.z+=a1.z; f1.w+=a1.w;
        f2.x+=a2.x; f2.y+=a2.y; f2.z+=a2.z; f2.w+=a2.w;
        f3.x+=a3.x; f3.y+=a3.y; f3.z+=a3.z; f3.w+=a3.w;
        if (ZERO) {
            const float4 z = make_float4(0.f,0.f,0.f,0.f);
            *(float4*)(sp+0)=z; *(float4*)(sp+4)=z; *(float4*)(sp+8)=z; *(float4*)(sp+12)=z;
        }
    }
    float sq = f0.x*f0.x+f0.y*f0.y+f0.z*f0.z+f0.w*f0.w
             + f1.x*f1.x+f1.y*f1.y+f1.z*f1.z+f1.w*f1.w
             + f2.x*f2.x+f2.y*f2.y+f2.z*f2.z+f2.w*f2.w
             + f3.x*f3.x+f3.y*f3.y+f3.z*f3.z+f3.w*f3.w;
    const float scale = sq / ((1.0f + sq) * sqrtf(sq + 1e-7f));
    float4 o0, o1, o2, o3;
    o0.x=f0.x*scale; o0.y=f0.y*scale; o0.z=f0.z*scale; o0.w=f0.w*scale;
    o1.x=f1.x*scale; o1.y=f1.y*scale; o1.z=f1.z*scale; o1.w=f1.w*scale;
    o2.x=f2.x*scale; o2.y=f2.y*scale; o2.z=f2.z*scale; o2.w=f2.w*scale;
    o3.x=f3.x*scale; o3.y=f3.y*scale; o3.z=f3.z*scale; o3.w=f3.w*scale;
    if (ADDP) {
        const float* pp = vprev + (size_t)t * 16;
        const float4 p0 = *(const float4*)(pp + 0);
        const float4 p1 = *(const float4*)(pp + 4);
        const float4 p2 = *(const float4*)(pp + 8);
        const float4 p3 = *(const float4*)(pp + 12);
        o0.x+=p0.x; o0.y+=p0.y; o0.z+=p0.z; o0.w+=p0.w;
        o1.x+=p1.x; o1.y+=p1.y; o1.z+=p1.z; o1.w+=p1.w;
        o2.x+=p2.x; o2.y+=p2.y; o2.z+=p2.z; o2.w+=p2.w;
        o3.x+=p3.x; o3.y+=p3.y; o3.z+=p3.z; o3.w+=p3.w;
    }
    float* vp = vout + (size_t)t * 16;
    *(float4*)(vp+0)=o0; *(float4*)(vp+4)=o1; *(float4*)(vp+8)=o2; *(float4*)(vp+12)=o3;
}

__global__ void legacy_zero(float* __restrict__ p)
{
    *(float4*)(p + ((size_t)blockIdx.x * 256 + threadIdx.x) * 4) =
        make_float4(0.f, 0.f, 0.f, 0.f);
}

extern "C" void kernel_launch(void* const* d_in, const int* in_sizes, int n_in,
                              void* d_out, int out_size, void* d_ws, size_t ws_size,
                              hipStream_t stream)
{
    const float* x = (const float*)d_in[0];   // [256, 4096, 8]
    const float* W = (const float*)d_in[1];   // [16, 4096, 16, 8]
    float* out = (float*)d_out;               // [256, 16, 16]

    // partial storage: 1024 tiles x 32768 elements
    const size_t need32 = (size_t)1024 * 32768 * 4 + 2 * 65536 * 4;  // 128.5 MiB
    const size_t need16 = (size_t)1024 * 32768 * 2 + 2 * 65536 * 4;  //  64.5 MiB

    if (ws_size >= need32) {
        float* part = (float*)d_ws;
        float* v1   = part + (size_t)1024 * 32768;
        float* vs   = v1 + 65536;
        caps_pass_part<0, 0><<<1024, 512, 0, stream>>>(x, W, nullptr, part);
        caps_squash_part<0, 0><<<128, 256, 0, stream>>>(part, v1, nullptr);
        caps_pass_part<1, 0><<<1024, 512, 0, stream>>>(x, W, v1, part);
        caps_squash_part<1, 0><<<128, 256, 0, stream>>>(part, vs, v1);
        caps_pass_part<1, 0><<<1024, 512, 0, stream>>>(x, W, vs, part);
        caps_squash_part<0, 0><<<128, 256, 0, stream>>>(part, out, nullptr);
    } else if (ws_size >= need16) {
        u16*  part = (u16*)d_ws;
        float* v1  = (float*)((char*)d_ws + (size_t)1024 * 32768 * 2);
        float* vs  = v1 + 65536;
        caps_pass_part<0, 1><<<1024, 512, 0, stream>>>(x, W, nullptr, part);
        caps_squash_part<0, 1><<<128, 256, 0, stream>>>(part, v1, nullptr);
        caps_pass_part<1, 1><<<1024, 512, 0, stream>>>(x, W, v1, part);
        caps_squash_part<1, 1><<<128, 256, 0, stream>>>(part, vs, v1);
        caps_pass_part<1, 1><<<1024, 512, 0, stream>>>(x, W, vs, part);
        caps_squash_part<0, 1><<<128, 256, 0, stream>>>(part, out, nullptr);
    } else {
        int R = 1;
        if (ws_size >= (size_t)(8 + 2) * 65536 * 4) R = 8;
        else if (ws_size >= (size_t)(2 + 2) * 65536 * 4) R = 2;
        float* srep = (float*)d_ws;
        float* v1   = srep + (size_t)R * 65536;
        float* vs   = v1 + 65536;
        legacy_zero<<<R * 64, 256, 0, stream>>>(srep);
        legacy_pass<0><<<256, 512, 0, stream>>>(x, W, nullptr, srep, R);
        legacy_squash<0, 1><<<16, 256, 0, stream>>>(srep, R, v1, nullptr);
        legacy_pass<1><<<256, 512, 0, stream>>>(x, W, v1, srep, R);
        legacy_squash<1, 1><<<16, 256, 0, stream>>>(srep, R, vs, v1);
        legacy_pass<1><<<256, 512, 0, stream>>>(x, W, vs, srep, R);
        legacy_squash<0, 0><<<16, 256, 0, stream>>>(srep, R, out, nullptr);
    }
}